// Round 9
// baseline (447.731 us; speedup 1.0000x reference)
//
#include <hip/hip_runtime.h>

// TopKRouter: logits = hs[32768,4096] @ gate_w[64,4096]^T ; top-2 + softmax.
// R9 = R8 router (unchanged, verified 172.5 us) + embedded DMA-stream
// microbenchmark: 3 barrier-free probes each streaming all 512 MB of A via
// global_load_lds at max MLP. dur_us = T_router + 3*T_probe decomposes the
// DMA-path ceiling from schedule coupling. Probes write only to d_ws+16MB.

#define NT    256
#define TT    32768
#define HD    4096
#define NE    64
#define BKT   32
#define NKT   128
#define BUFB  25600          // bytes per LDS A buffer (64 rows x 400 B)
#define ALIM  ((size_t)TT * HD * 4 - 16)

typedef __attribute__((ext_vector_type(8))) short bf16x8;
typedef __attribute__((ext_vector_type(4))) float f32x4;

#define MFMA __builtin_amdgcn_mfma_f32_16x16x32_bf16

__device__ __forceinline__ bf16x8 u2b(uint4 u) { return __builtin_bit_cast(bf16x8, u); }
__device__ __forceinline__ float4 b4f(uint4 u) { return __builtin_bit_cast(float4, u); }

__device__ __forceinline__ void gload_lds16(const void* g, void* l) {
  __builtin_amdgcn_global_load_lds(
      (const __attribute__((address_space(1))) void*)g,
      (__attribute__((address_space(3))) void*)l, 16, 0, 0);
}

// Exact 3-limb truncation split of 8 f32 -> 3 packed bf16x8 (as uint4).
__device__ __forceinline__ void tsplit8(float4 a, float4 b,
                                        uint4& o0, uint4& o1, uint4& o2) {
  float f[8] = {a.x, a.y, a.z, a.w, b.x, b.y, b.z, b.w};
  unsigned p0[4], p1[4], p2[4];
#pragma unroll
  for (int j = 0; j < 4; ++j) {
    float x0 = f[2 * j], x1 = f[2 * j + 1];
    unsigned u0 = __float_as_uint(x0) & 0xffff0000u;
    unsigned u1 = __float_as_uint(x1) & 0xffff0000u;
    float r0 = x0 - __uint_as_float(u0);
    float r1 = x1 - __uint_as_float(u1);
    unsigned v0 = __float_as_uint(r0) & 0xffff0000u;
    unsigned v1 = __float_as_uint(r1) & 0xffff0000u;
    float s0 = r0 - __uint_as_float(v0);
    float s1 = r1 - __uint_as_float(v1);
    p0[j] = (u0 >> 16) | u1;
    p1[j] = (v0 >> 16) | v1;
    p2[j] = (__float_as_uint(s0) >> 16) | (__float_as_uint(s1) & 0xffff0000u);
  }
  o0 = make_uint4(p0[0], p0[1], p0[2], p0[3]);
  o1 = make_uint4(p1[0], p1[1], p1[2], p1[3]);
  o2 = make_uint4(p2[0], p2[1], p2[2], p2[3]);
}

// ---- Pre-kernel: pack gate_w into fragment-major bf16 limb blocks ----
__global__ __launch_bounds__(256)
void prepack_w_kernel(const float* __restrict__ W, uint4* __restrict__ Bp) {
  const int t  = blockIdx.x * 256 + threadIdx.x;
  const int e  = t >> 9;
  const int k0 = (t & 511) * 8;
  const float4* wp = (const float4*)(W + (size_t)e * HD + k0);
  uint4 o0, o1, o2;
  tsplit8(wp[0], wp[1], o0, o1, o2);
  const int ts = k0 >> 5;
  const int lg = (k0 >> 3) & 3;
  const int f  = e >> 4;
  const int ln = lg * 16 + (e & 15);
  Bp[(((ts * 3 + 0) * 4 + f) << 6) + ln] = o0;
  Bp[(((ts * 3 + 1) * 4 + f) << 6) + ln] = o1;
  Bp[(((ts * 3 + 2) * 4 + f) << 6) + ln] = o2;
}

// ---- DMA-stream probe: barrier-free, max-MLP read of A via global_load_lds.
// Each wave: 256 x 1-KB contiguous bursts into an 8-slot private LDS ring.
// No consumers, no barriers -> measures the pure DMA read ceiling.
__global__ __launch_bounds__(256)
void probe_dma_stream(const float* __restrict__ A, float* __restrict__ sink) {
  __shared__ __align__(16) unsigned char pbuf[32768];   // 4 waves x 8 KB
  const int tid  = threadIdx.x;
  const int w    = tid >> 6;
  const int lane = tid & 63;
  const char* src = (const char*)A + ((size_t)blockIdx.x << 20)
                    + ((size_t)w << 18) + (size_t)lane * 16;
  unsigned char* dst = pbuf + w * 8192;
#pragma unroll 1
  for (int i = 0; i < 64; ++i) {
    const int s4 = (i & 1) ? 4096 : 0;
    gload_lds16(src,        dst + s4);
    gload_lds16(src + 1024, dst + s4 + 1024);
    gload_lds16(src + 2048, dst + s4 + 2048);
    gload_lds16(src + 3072, dst + s4 + 3072);
    src += 4096;
  }
  asm volatile("s_waitcnt vmcnt(0)" ::: "memory");
  if (tid == 0 && sink) sink[blockIdx.x] = 1.0f;
}

#define PROD1(AM0, AM1, BN0, BN1) \
    acc00 = MFMA(AM0, BN0, acc00, 0, 0, 0); \
    acc01 = MFMA(AM0, BN1, acc01, 0, 0, 0); \
    acc10 = MFMA(AM1, BN0, acc10, 0, 0, 0); \
    acc11 = MFMA(AM1, BN1, acc11, 0, 0, 0);

// ---- Main kernel (UNCHANGED from R8, verified 172.5 us) ----
__global__ __launch_bounds__(NT, 2)
void router_dma_kernel(const float* __restrict__ A, const uint4* __restrict__ Bp,
                       float* __restrict__ outw, float* __restrict__ outi,
                       float* __restrict__ outl) {
  __shared__ __align__(16) unsigned char smem[2 * BUFB];   // 51,200 B

  const int tid  = threadIdx.x;
  const int bm   = blockIdx.x;
  const int lane = tid & 63;
  const int w    = tid >> 6;     // wave 0..3
  const int wr   = w >> 1;       // row half
  const int wc   = w & 1;        // expert half
  const int l15  = lane & 15;
  const int lg   = lane >> 4;    // 0..3

  const char* Abytes = (const char*)A;

  size_t srcoff[7];
#pragma unroll
  for (int j = 0; j < 7; ++j) {
    int ii = j * 4 + w;
    int f  = ii * 1024 + lane * 16;
    int r  = f / 400, rb = f % 400;
    srcoff[j] = (size_t)(bm * 64 + r) * (HD * 4) + (size_t)(rb < 384 ? rb : 0);
  }

#define DMA_ISSUE(CT, BOFF) { \
    _Pragma("unroll") \
    for (int j = 0; j < 7; ++j) { \
      int ii = j * 4 + w; \
      if (ii < 25) { \
        size_t off = srcoff[j] + (size_t)(CT) * 384; \
        if (off > ALIM) off -= (size_t)(HD * 4); \
        gload_lds16(Abytes + off, smem + (BOFF) + ii * 1024); \
      } \
    } \
    __builtin_amdgcn_sched_barrier(0); }

  const int row0b = (wr * 32 + l15) * 400;
  const int row1b = row0b + 16 * 400;
  const int lgb   = lg * 32;

  const uint4* pbB = Bp + wc * 128 + lane;

  f32x4 acc00 = {0.f,0.f,0.f,0.f}, acc01 = {0.f,0.f,0.f,0.f};
  f32x4 acc10 = {0.f,0.f,0.f,0.f}, acc11 = {0.f,0.f,0.f,0.f};

  uint4 bA0f0, bA0f1, bA1f0, bA1f1, bA2f0, bA2f1;
  uint4 bB0f0, bB0f1, bB1f0, bB1f1, bB2f0, bB2f1;

#define LOADB(SET, G) { \
    const uint4* q_ = pbB + (size_t)(G) * 768; \
    SET##0f0 = q_[0];   SET##0f1 = q_[64]; \
    SET##1f0 = q_[256]; SET##1f1 = q_[320]; \
    SET##2f0 = q_[512]; SET##2f1 = q_[576]; }

#define BSTEP(BOFF, S, BU, BL, GN, DOLOAD) { \
    if (DOLOAD) { LOADB(BL, GN) } \
    uint4 rA0lo = *(const uint4*)(smem + (BOFF) + row0b + (S) * 128 + lgb); \
    uint4 rA0hi = *(const uint4*)(smem + (BOFF) + row0b + (S) * 128 + lgb + 16); \
    uint4 rA1lo = *(const uint4*)(smem + (BOFF) + row1b + (S) * 128 + lgb); \
    uint4 rA1hi = *(const uint4*)(smem + (BOFF) + row1b + (S) * 128 + lgb + 16); \
    uint4 x0, x1, x2, y0, y1, y2; \
    tsplit8(b4f(rA0lo), b4f(rA0hi), x0, x1, x2); \
    tsplit8(b4f(rA1lo), b4f(rA1hi), y0, y1, y2); \
    const bf16x8 a0m0 = u2b(x0), a1m0 = u2b(x1), a2m0 = u2b(x2); \
    const bf16x8 a0m1 = u2b(y0), a1m1 = u2b(y1), a2m1 = u2b(y2); \
    PROD1(a0m0, a0m1, u2b(BU##2f0), u2b(BU##2f1)) \
    PROD1(a1m0, a1m1, u2b(BU##1f0), u2b(BU##1f1)) \
    PROD1(a2m0, a2m1, u2b(BU##0f0), u2b(BU##0f1)) \
    PROD1(a0m0, a0m1, u2b(BU##1f0), u2b(BU##1f1)) \
    PROD1(a1m0, a1m1, u2b(BU##0f0), u2b(BU##0f1)) \
    PROD1(a0m0, a0m1, u2b(BU##0f0), u2b(BU##0f1)) }

  DMA_ISSUE(0, 0)
  LOADB(bA, 0)
  __syncthreads();

#pragma unroll 1
  for (int ot = 0; ot < 21; ++ot) {
    const int g0 = ot * 6;
    DMA_ISSUE(2 * ot + 1, BUFB)
    BSTEP(0, 0, bA, bB, g0 + 1, true)
    BSTEP(0, 1, bB, bA, g0 + 2, true)
    BSTEP(0, 2, bA, bB, g0 + 3, true)
    __syncthreads();
    DMA_ISSUE(2 * ot + 2, 0)
    BSTEP(BUFB, 0, bB, bA, g0 + 4, true)
    BSTEP(BUFB, 1, bA, bB, g0 + 5, true)
    BSTEP(BUFB, 2, bB, bA, g0 + 6, true)
    __syncthreads();
  }

  BSTEP(0, 0, bA, bB, 127, true)
  BSTEP(0, 1, bB, bA, 0, false)

  const int t0 = bm * 64;
  float* lf = (float*)smem;

  __syncthreads();

#define EPO(MI, NI, ACC) \
  { _Pragma("unroll") \
    for (int r = 0; r < 4; ++r) { \
      int tl = wr * 32 + (MI) * 16 + lg * 4 + r; \
      int e  = wc * 32 + (NI) * 16 + l15; \
      float v = ACC[r]; \
      outl[(size_t)(t0 + tl) * NE + e] = v; \
      lf[tl * 65 + e] = v; \
    } }
  EPO(0, 0, acc00) EPO(0, 1, acc01) EPO(1, 0, acc10) EPO(1, 1, acc11)
#undef EPO

  __syncthreads();

  if (tid < 64) {
    const int t = tid;
    float m1 = -1e30f, m2 = -1e30f;
    int i1 = 0, i2 = 0;
#pragma unroll
    for (int e = 0; e < NE; ++e) {
      float v = lf[t * 65 + e];
      if (v > m1)      { m2 = m1; i2 = i1; m1 = v; i1 = e; }
      else if (v > m2) { m2 = v; i2 = e; }
    }
    float e2  = expf(m2 - m1);
    float inv = 1.0f / (1.0f + e2);
    outw[(size_t)(t0 + t) * 2 + 0] = inv;
    outw[(size_t)(t0 + t) * 2 + 1] = e2 * inv;
    outi[(size_t)(t0 + t) * 2 + 0] = (float)i1;
    outi[(size_t)(t0 + t) * 2 + 1] = (float)i2;
  }
}

// ---- Fallback (R3 LDS kernel, verified): used only if ws_size too small ----
__global__ __launch_bounds__(256, 2)
void topk_router_lds(const float* __restrict__ A, const float* __restrict__ W,
                     float* __restrict__ outw, float* __restrict__ outi,
                     float* __restrict__ outl) {
  __shared__ __align__(16) unsigned char smem[49152];
  const int tid  = threadIdx.x;
  const int bm   = blockIdx.x;
  const int lane = tid & 63;
  const int wid  = tid >> 6;
  const int wr   = wid >> 1;
  const int wc   = wid & 1;
  const int l15  = lane & 15;
  const int lg   = lane >> 4;
  const int s_r  = tid >> 2;
  const int s_cb = (tid & 3) << 3;
  const float* aball = A + (size_t)(bm * 64 + s_r) * HD + s_cb;
  const float* bball = W + (size_t)s_r * HD + s_cb;
  const unsigned wswz  = ((unsigned)((s_r >> 1) & 3)) << 4;
  const unsigned wbyte = (unsigned)(s_r * 64) + (((unsigned)(s_cb * 2)) ^ wswz);
  f32x4 acc00 = {0.f,0.f,0.f,0.f}, acc01 = {0.f,0.f,0.f,0.f};
  f32x4 acc10 = {0.f,0.f,0.f,0.f}, acc11 = {0.f,0.f,0.f,0.f};
  float4 aE0, aE1, bE0, bE1, aO0, aO1, bO0, bO1;
#define LOADS(T, A0, A1, B0, B1) { \
    const float4* ap = (const float4*)(aball + (size_t)(T) * BKT); \
    A0 = ap[0]; A1 = ap[1]; \
    const float4* bp = (const float4*)(bball + (size_t)(T) * BKT); \
    B0 = bp[0]; B1 = bp[1]; }
#define CONVW2(BB, A0, A1, B0, B1) { \
    uint4 o0, o1, o2; \
    tsplit8(A0, A1, o0, o1, o2); \
    *(uint4*)(smem + (BB) +     0 + wbyte) = o0; \
    *(uint4*)(smem + (BB) +  4096 + wbyte) = o1; \
    *(uint4*)(smem + (BB) +  8192 + wbyte) = o2; \
    tsplit8(B0, B1, o0, o1, o2); \
    *(uint4*)(smem + (BB) + 12288 + wbyte) = o0; \
    *(uint4*)(smem + (BB) + 16384 + wbyte) = o1; \
    *(uint4*)(smem + (BB) + 20480 + wbyte) = o2; }
  auto compute = [&](int bb) {
    bf16x8 a0m0, a0m1, a1m0, a1m1, a2m0, a2m1;
    bf16x8 b0n0, b0n1, b1n0, b1n1, b2n0, b2n1;
    const unsigned kb = (unsigned)(lg * 16);
#define LDA(SI, MI, DST) { \
    int row = wr * 32 + (MI) * 16 + l15; \
    DST = *(const bf16x8*)(smem + bb + (SI) * 4096 + row * 64 + \
          (kb ^ ((((unsigned)row >> 1) & 3) << 4))); }
#define LDB(SI, NI, DST) { \
    int row = wc * 32 + (NI) * 16 + l15; \
    DST = *(const bf16x8*)(smem + bb + 12288 + (SI) * 4096 + row * 64 + \
          (kb ^ ((((unsigned)row >> 1) & 3) << 4))); }
    LDA(0, 0, a0m0) LDA(0, 1, a0m1)
    LDA(1, 0, a1m0) LDA(1, 1, a1m1)
    LDA(2, 0, a2m0) LDA(2, 1, a2m1)
    LDB(0, 0, b0n0) LDB(0, 1, b0n1)
    LDB(1, 0, b1n0) LDB(1, 1, b1n1)
    LDB(2, 0, b2n0) LDB(2, 1, b2n1)
#undef LDA
#undef LDB
    PROD1(a0m0, a0m1, b2n0, b2n1)
    PROD1(a1m0, a1m1, b1n0, b1n1)
    PROD1(a2m0, a2m1, b0n0, b0n1)
    PROD1(a0m0, a0m1, b1n0, b1n1)
    PROD1(a1m0, a1m1, b0n0, b0n1)
    PROD1(a0m0, a0m1, b0n0, b0n1)
  };
  LOADS(0, aE0, aE1, bE0, bE1)
  LOADS(1, aO0, aO1, bO0, bO1)
  CONVW2(0, aE0, aE1, bE0, bE1)
  __syncthreads();
#pragma unroll 1
  for (int kk = 0; kk < NKT; kk += 2) {
    if (kk + 2 < NKT) { LOADS(kk + 2, aE0, aE1, bE0, bE1) }
    __builtin_amdgcn_sched_barrier(0);
    compute(0);
    CONVW2(24576, aO0, aO1, bO0, bO1)
    __syncthreads();
    if (kk + 3 < NKT) { LOADS(kk + 3, aO0, aO1, bO0, bO1) }
    __builtin_amdgcn_sched_barrier(0);
    compute(24576);
    if (kk + 2 < NKT) { CONVW2(0, aE0, aE1, bE0, bE1) }
    __syncthreads();
  }
  const int t0 = bm * 64;
  float* lf2 = (float*)smem;
#define EPI(MI, NI, ACC) \
  { _Pragma("unroll") \
    for (int r = 0; r < 4; ++r) { \
      int tl = wr * 32 + (MI) * 16 + lg * 4 + r; \
      int e  = wc * 32 + (NI) * 16 + l15; \
      float v = ACC[r]; \
      outl[(size_t)(t0 + tl) * NE + e] = v; \
      lf2[tl * 65 + e] = v; \
    } }
  EPI(0, 0, acc00) EPI(0, 1, acc01) EPI(1, 0, acc10) EPI(1, 1, acc11)
#undef EPI
  __syncthreads();
  if (tid < 64) {
    const int t = tid;
    float m1 = -1e30f, m2 = -1e30f;
    int i1 = 0, i2 = 0;
#pragma unroll
    for (int e = 0; e < NE; ++e) {
      float v = lf2[t * 65 + e];
      if (v > m1)      { m2 = m1; i2 = i1; m1 = v; i1 = e; }
      else if (v > m2) { m2 = v; i2 = e; }
    }
    float e2  = expf(m2 - m1);
    float inv = 1.0f / (1.0f + e2);
    outw[(size_t)(t0 + t) * 2 + 0] = inv;
    outw[(size_t)(t0 + t) * 2 + 1] = e2 * inv;
    outi[(size_t)(t0 + t) * 2 + 0] = (float)i1;
    outi[(size_t)(t0 + t) * 2 + 1] = (float)i2;
  }
}

extern "C" void kernel_launch(void* const* d_in, const int* in_sizes, int n_in,
                              void* d_out, int out_size, void* d_ws, size_t ws_size,
                              hipStream_t stream) {
  (void)in_sizes; (void)n_in; (void)out_size;
  const float* A = (const float*)d_in[0];   // hidden_states [32768][4096] f32
  const float* W = (const float*)d_in[1];   // gate_w [64][4096] f32
  float* outw = (float*)d_out;              // [T][2] weights
  float* outi = (float*)d_out + 2 * TT;     // [T][2] indices AS FLOATS
  float* outl = (float*)d_out + 4 * TT;     // [T][64] logits

  const size_t need = (size_t)NKT * 3 * 4 * 1024;   // 1.5 MiB packed B
  if (ws_size >= need) {
    hipLaunchKernelGGL(prepack_w_kernel, dim3(128), dim3(256), 0, stream,
                       W, (uint4*)d_ws);
    hipLaunchKernelGGL(router_dma_kernel, dim3(TT / 64), dim3(NT), 0, stream,
                       A, (const uint4*)d_ws, outw, outi, outl);
  } else {
    hipLaunchKernelGGL(topk_router_lds, dim3(TT / 64), dim3(256), 0, stream,
                       A, W, outw, outi, outl);
  }

  // ---- Embedded microbenchmark: 3x barrier-free DMA stream of A ----
  // dur_us = T_router + 3*T_probe. Decision tree in the round notes.
  float* sink = (ws_size >= ((size_t)32 << 20))
                  ? (float*)((char*)d_ws + ((size_t)16 << 20)) : nullptr;
  for (int r = 0; r < 3; ++r) {
    hipLaunchKernelGGL(probe_dma_stream, dim3(512), dim3(256), 0, stream,
                       A, sink);
  }
}

// Round 10
// 170.331 us; speedup vs baseline: 2.6286x; 2.6286x over previous
//
#include <hip/hip_runtime.h>

// TopKRouter: logits = hs[32768,4096] @ gate_w[64,4096]^T ; top-2 + softmax.
// f32 GEMM via 3-limb truncation split (6 MFMA products, si+sj<=2); limb
// values and per-accumulator product order identical to verified R3..R9.
//
// R10: never-drain counted-vmcnt DMA pipeline (probe-validated mechanism:
// barrier-free global_load_lds streams at 5.85 TB/s, R9).
//  - 3 LDS buffers x 16 KB (supertile = 2 K-steps, 64 rows x 256 B).
//  - DMA issued 2 supertiles ahead; B limbs (prepacked fragment-major table,
//    L2-resident) register-loaded 1 supertile ahead (double-named sets).
//  - Each half-iter region = exactly 16 VMEM ops/wave (12 B + 4 DMA), fenced
//    by asm memory clobbers -> `s_waitcnt vmcnt(16)` at iter top retires
//    precisely through buffer st's DMA; raw s_barrier; NO vmcnt(0) anywhere.
//  - LDS bank conflicts: linear LDS dest + pre-swizzled GLOBAL source +
//    swizzled read (granule g ^= row&7), per rule #21.

#define NT    256
#define TT    32768
#define HD    4096
#define NE    64
#define NST   64             // supertiles (2 K-steps each)
#define BUFB  16384u         // bytes per LDS A buffer
#define NBUF  3

typedef __attribute__((ext_vector_type(8))) short bf16x8;
typedef __attribute__((ext_vector_type(4))) float f32x4;

#define MFMA __builtin_amdgcn_mfma_f32_16x16x32_bf16

__device__ __forceinline__ bf16x8 u2b(uint4 u) { return __builtin_bit_cast(bf16x8, u); }
__device__ __forceinline__ float4 b4f(uint4 u) { return __builtin_bit_cast(float4, u); }

__device__ __forceinline__ void gload_lds16(const void* g, void* l) {
  __builtin_amdgcn_global_load_lds(
      (const __attribute__((address_space(1))) void*)g,
      (__attribute__((address_space(3))) void*)l, 16, 0, 0);
}

// Exact 3-limb truncation split of 8 f32 -> 3 packed bf16x8 (as uint4).
__device__ __forceinline__ void tsplit8(float4 a, float4 b,
                                        uint4& o0, uint4& o1, uint4& o2) {
  float f[8] = {a.x, a.y, a.z, a.w, b.x, b.y, b.z, b.w};
  unsigned p0[4], p1[4], p2[4];
#pragma unroll
  for (int j = 0; j < 4; ++j) {
    float x0 = f[2 * j], x1 = f[2 * j + 1];
    unsigned u0 = __float_as_uint(x0) & 0xffff0000u;
    unsigned u1 = __float_as_uint(x1) & 0xffff0000u;
    float r0 = x0 - __uint_as_float(u0);
    float r1 = x1 - __uint_as_float(u1);
    unsigned v0 = __float_as_uint(r0) & 0xffff0000u;
    unsigned v1 = __float_as_uint(r1) & 0xffff0000u;
    float s0 = r0 - __uint_as_float(v0);
    float s1 = r1 - __uint_as_float(v1);
    p0[j] = (u0 >> 16) | u1;
    p1[j] = (v0 >> 16) | v1;
    p2[j] = (__float_as_uint(s0) >> 16) | (__float_as_uint(s1) & 0xffff0000u);
  }
  o0 = make_uint4(p0[0], p0[1], p0[2], p0[3]);
  o1 = make_uint4(p1[0], p1[1], p1[2], p1[3]);
  o2 = make_uint4(p2[0], p2[1], p2[2], p2[3]);
}

// ---- Pre-kernel: pack gate_w into fragment-major bf16 limb blocks ----
// uint4 index = ((g*3+s)*4+f)*64 + (lg*16 + (e&15)); g = K-step. (R7-verified)
__global__ __launch_bounds__(256)
void prepack_w_kernel(const float* __restrict__ W, uint4* __restrict__ Bp) {
  const int t  = blockIdx.x * 256 + threadIdx.x;
  const int e  = t >> 9;
  const int k0 = (t & 511) * 8;
  const float4* wp = (const float4*)(W + (size_t)e * HD + k0);
  uint4 o0, o1, o2;
  tsplit8(wp[0], wp[1], o0, o1, o2);
  const int ts = k0 >> 5;
  const int lg = (k0 >> 3) & 3;
  const int f  = e >> 4;
  const int ln = lg * 16 + (e & 15);
  Bp[(((ts * 3 + 0) * 4 + f) << 6) + ln] = o0;
  Bp[(((ts * 3 + 1) * 4 + f) << 6) + ln] = o1;
  Bp[(((ts * 3 + 2) * 4 + f) << 6) + ln] = o2;
}

#define PROD1(AM0, AM1, BN0, BN1) \
    acc00 = MFMA(AM0, BN0, acc00, 0, 0, 0); \
    acc01 = MFMA(AM0, BN1, acc01, 0, 0, 0); \
    acc10 = MFMA(AM1, BN0, acc10, 0, 0, 0); \
    acc11 = MFMA(AM1, BN1, acc11, 0, 0, 0);

// ---- Main kernel ----
__global__ __launch_bounds__(NT, 2)
void router_pipe_kernel(const float* __restrict__ A, const uint4* __restrict__ Bp,
                        float* __restrict__ outw, float* __restrict__ outi,
                        float* __restrict__ outl) {
  __shared__ __align__(16) unsigned char smem[NBUF * BUFB];   // 49,152 B

  const int tid  = threadIdx.x;
  const int bm   = blockIdx.x;
  const int lane = tid & 63;
  const int w    = tid >> 6;     // wave 0..3
  const int wr   = w >> 1;       // row half
  const int wc   = w & 1;        // expert half
  const int l15  = lane & 15;
  const int lg   = lane >> 4;    // 0..3
  const int x7   = l15 & 7;      // read-side swizzle key (row&7 == l15&7)

  const char* Ab = (const char*)A;

  // DMA source offsets (pre-swizzled global source, LDS dest linear).
  // instr i = w*4+j; LDS row = i*4 + (lane>>4); dest granule g' = lane&15;
  // source granule = g' ^ (row&7).
  unsigned soff[4];
#pragma unroll
  for (int j = 0; j < 4; ++j) {
    int rj = w * 16 + j * 4 + lg;
    int gs = l15 ^ (rj & 7);
    soff[j] = (unsigned)((bm * 64 + rj) * (HD * 4)) + (unsigned)(gs * 16);
  }

#define DMA(T, BD) { \
    const int tc_ = (T) > (NST - 1) ? (NST - 1) : (T); \
    _Pragma("unroll") \
    for (int j = 0; j < 4; ++j) \
      gload_lds16(Ab + (size_t)soff[j] + (size_t)tc_ * 256, \
                  smem + (BD) + (unsigned)((w * 4 + j) * 1024)); }

  // B limb table: per K-step g, limb L, frag F: uint4 idx = (g*3+L)*256 + F*64 + lane.
  const uint4* pbB = Bp + wc * 128 + lane;

#define LOADB(P, T) { \
    const int tc_ = (T) > (NST - 1) ? (NST - 1) : (T); \
    const uint4* q_ = pbB + (size_t)tc_ * 1536; \
    P##s0L0f0 = q_[0];    P##s0L0f1 = q_[64]; \
    P##s0L1f0 = q_[256];  P##s0L1f1 = q_[320]; \
    P##s0L2f0 = q_[512];  P##s0L2f1 = q_[576]; \
    P##s1L0f0 = q_[768];  P##s1L0f1 = q_[832]; \
    P##s1L1f0 = q_[1024]; P##s1L1f1 = q_[1088]; \
    P##s1L2f0 = q_[1280]; P##s1L2f1 = q_[1344]; }

  uint4 Es0L0f0, Es0L0f1, Es0L1f0, Es0L1f1, Es0L2f0, Es0L2f1;
  uint4 Es1L0f0, Es1L0f1, Es1L1f0, Es1L1f1, Es1L2f0, Es1L2f1;
  uint4 Os0L0f0, Os0L0f1, Os0L1f0, Os0L1f1, Os0L2f0, Os0L2f1;
  uint4 Os1L0f0, Os1L0f1, Os1L1f0, Os1L1f1, Os1L2f0, Os1L2f1;

  f32x4 acc00 = {0.f,0.f,0.f,0.f}, acc01 = {0.f,0.f,0.f,0.f};
  f32x4 acc10 = {0.f,0.f,0.f,0.f}, acc11 = {0.f,0.f,0.f,0.f};

  const unsigned r0base = (unsigned)((wr * 32 + l15) * 256);

  // One K-step: 4 swizzled ds_read_b128 (raw A), 2 tsplit8, 24 MFMA
  // (product order identical to R3's verified kernel).
#define BSTEPX(BC, S, B0f0, B0f1, B1f0, B1f1, B2f0, B2f1) { \
    const int gi_ = (S) * 8 + lg * 2; \
    const unsigned glo_ = (unsigned)((gi_ ^ x7) << 4); \
    const unsigned ghi_ = (unsigned)(((gi_ + 1) ^ x7) << 4); \
    const unsigned char* b0_ = smem + (BC) + r0base; \
    const unsigned char* b1_ = b0_ + 16 * 256; \
    uint4 a0lo = *(const uint4*)(b0_ + glo_); \
    uint4 a0hi = *(const uint4*)(b0_ + ghi_); \
    uint4 a1lo = *(const uint4*)(b1_ + glo_); \
    uint4 a1hi = *(const uint4*)(b1_ + ghi_); \
    uint4 x0_, x1_, x2_, y0_, y1_, y2_; \
    tsplit8(b4f(a0lo), b4f(a0hi), x0_, x1_, x2_); \
    tsplit8(b4f(a1lo), b4f(a1hi), y0_, y1_, y2_); \
    const bf16x8 a0m0 = u2b(x0_), a1m0 = u2b(x1_), a2m0 = u2b(x2_); \
    const bf16x8 a0m1 = u2b(y0_), a1m1 = u2b(y1_), a2m1 = u2b(y2_); \
    PROD1(a0m0, a0m1, u2b(B2f0), u2b(B2f1)) \
    PROD1(a1m0, a1m1, u2b(B1f0), u2b(B1f1)) \
    PROD1(a2m0, a2m1, u2b(B0f0), u2b(B0f1)) \
    PROD1(a0m0, a0m1, u2b(B1f0), u2b(B1f1)) \
    PROD1(a1m0, a1m1, u2b(B0f0), u2b(B0f1)) \
    PROD1(a0m0, a0m1, u2b(B0f0), u2b(B0f1)) }

#define COMPUTE2(BC, P) \
    BSTEPX(BC, 0, P##s0L0f0, P##s0L0f1, P##s0L1f0, P##s0L1f1, P##s0L2f0, P##s0L2f1) \
    BSTEPX(BC, 1, P##s1L0f0, P##s1L0f1, P##s1L1f0, P##s1L1f1, P##s1L2f0, P##s1L2f1)

  // Half-iteration: region = exactly 16 VMEM ops/wave (12 B + 4 DMA).
#define HALF(ST, LOADSET, COMPSET) { \
    asm volatile("s_waitcnt vmcnt(16)" ::: "memory"); \
    __builtin_amdgcn_s_barrier(); \
    __builtin_amdgcn_sched_barrier(0); \
    LOADB(LOADSET, (ST) + 1) \
    DMA((ST) + 2, bd) \
    __builtin_amdgcn_sched_barrier(0); \
    COMPUTE2(bc, COMPSET) \
    bc += BUFB; if (bc == NBUF * BUFB) bc = 0; \
    bd += BUFB; if (bd == NBUF * BUFB) bd = 0; }

  // Prologue: region A = DMA(0) [4 ops]; fence; region B = LOADB(0)+DMA(1) [16 ops].
  DMA(0, 0u)
  asm volatile("" ::: "memory");
  LOADB(E, 0)
  DMA(1, BUFB)

  unsigned bc = 0, bd = 2 * BUFB;

#pragma unroll 1
  for (int p = 0; p < NST / 2; ++p) {
    HALF(2 * p,     O, E)     // compute supertile 2p   (B set E), load B(2p+1)->O
    HALF(2 * p + 1, E, O)     // compute supertile 2p+1 (B set O), load B(2p+2)->E
  }

  // Full drain before LDS reuse (late clamped DMAs land in buf1/buf2).
  asm volatile("s_waitcnt vmcnt(0)" ::: "memory");
  __syncthreads();

  // ---- Epilogue: logits to global + LDS, then top-2 + softmax ----
  const int t0 = bm * 64;
  float* lf = (float*)smem;               // [64][65] f32 = 16,640 B

#define EPO(MI, NI, ACC) \
  { _Pragma("unroll") \
    for (int r = 0; r < 4; ++r) { \
      int tl = wr * 32 + (MI) * 16 + lg * 4 + r; \
      int e  = wc * 32 + (NI) * 16 + l15; \
      float v = ACC[r]; \
      outl[(size_t)(t0 + tl) * NE + e] = v; \
      lf[tl * 65 + e] = v; \
    } }
  EPO(0, 0, acc00) EPO(0, 1, acc01) EPO(1, 0, acc10) EPO(1, 1, acc11)
#undef EPO

  __syncthreads();

  if (tid < 64) {
    const int t = tid;
    float m1 = -1e30f, m2 = -1e30f;
    int i1 = 0, i2 = 0;
#pragma unroll
    for (int e = 0; e < NE; ++e) {
      float v = lf[t * 65 + e];
      if (v > m1)      { m2 = m1; i2 = i1; m1 = v; i1 = e; }
      else if (v > m2) { m2 = v; i2 = e; }
    }
    float e2  = expf(m2 - m1);
    float inv = 1.0f / (1.0f + e2);
    outw[(size_t)(t0 + t) * 2 + 0] = inv;
    outw[(size_t)(t0 + t) * 2 + 1] = e2 * inv;
    outi[(size_t)(t0 + t) * 2 + 0] = (float)i1;   // indices as floats
    outi[(size_t)(t0 + t) * 2 + 1] = (float)i2;
  }
}

// ---- Fallback (R3 LDS kernel, verified): used only if ws_size too small ----
__global__ __launch_bounds__(256, 2)
void topk_router_lds(const float* __restrict__ A, const float* __restrict__ W,
                     float* __restrict__ outw, float* __restrict__ outi,
                     float* __restrict__ outl) {
  __shared__ __align__(16) unsigned char smem[49152];
  const int tid  = threadIdx.x;
  const int bm   = blockIdx.x;
  const int lane = tid & 63;
  const int wid  = tid >> 6;
  const int wr   = wid >> 1;
  const int wc   = wid & 1;
  const int l15  = lane & 15;
  const int lg   = lane >> 4;
  const int s_r  = tid >> 2;
  const int s_cb = (tid & 3) << 3;
  const float* aball = A + (size_t)(bm * 64 + s_r) * HD + s_cb;
  const float* bball = W + (size_t)s_r * HD + s_cb;
  const unsigned wswz  = ((unsigned)((s_r >> 1) & 3)) << 4;
  const unsigned wbyte = (unsigned)(s_r * 64) + (((unsigned)(s_cb * 2)) ^ wswz);
  f32x4 acc00 = {0.f,0.f,0.f,0.f}, acc01 = {0.f,0.f,0.f,0.f};
  f32x4 acc10 = {0.f,0.f,0.f,0.f}, acc11 = {0.f,0.f,0.f,0.f};
  float4 aE0, aE1, bE0, bE1, aO0, aO1, bO0, bO1;
#define LOADS(T, A0, A1, B0, B1) { \
    const float4* ap = (const float4*)(aball + (size_t)(T) * 32); \
    A0 = ap[0]; A1 = ap[1]; \
    const float4* bp = (const float4*)(bball + (size_t)(T) * 32); \
    B0 = bp[0]; B1 = bp[1]; }
#define CONVW2(BB, A0, A1, B0, B1) { \
    uint4 o0, o1, o2; \
    tsplit8(A0, A1, o0, o1, o2); \
    *(uint4*)(smem + (BB) +     0 + wbyte) = o0; \
    *(uint4*)(smem + (BB) +  4096 + wbyte) = o1; \
    *(uint4*)(smem + (BB) +  8192 + wbyte) = o2; \
    tsplit8(B0, B1, o0, o1, o2); \
    *(uint4*)(smem + (BB) + 12288 + wbyte) = o0; \
    *(uint4*)(smem + (BB) + 16384 + wbyte) = o1; \
    *(uint4*)(smem + (BB) + 20480 + wbyte) = o2; }
  auto compute = [&](int bb) {
    bf16x8 a0m0, a0m1, a1m0, a1m1, a2m0, a2m1;
    bf16x8 b0n0, b0n1, b1n0, b1n1, b2n0, b2n1;
    const unsigned kb = (unsigned)(lg * 16);
#define LDA(SI, MI, DST) { \
    int row = wr * 32 + (MI) * 16 + l15; \
    DST = *(const bf16x8*)(smem + bb + (SI) * 4096 + row * 64 + \
          (kb ^ ((((unsigned)row >> 1) & 3) << 4))); }
#define LDB(SI, NI, DST) { \
    int row = wc * 32 + (NI) * 16 + l15; \
    DST = *(const bf16x8*)(smem + bb + 12288 + (SI) * 4096 + row * 64 + \
          (kb ^ ((((unsigned)row >> 1) & 3) << 4))); }
    LDA(0, 0, a0m0) LDA(0, 1, a0m1)
    LDA(1, 0, a1m0) LDA(1, 1, a1m1)
    LDA(2, 0, a2m0) LDA(2, 1, a2m1)
    LDB(0, 0, b0n0) LDB(0, 1, b0n1)
    LDB(1, 0, b1n0) LDB(1, 1, b1n1)
    LDB(2, 0, b2n0) LDB(2, 1, b2n1)
#undef LDA
#undef LDB
    PROD1(a0m0, a0m1, b2n0, b2n1)
    PROD1(a1m0, a1m1, b1n0, b1n1)
    PROD1(a2m0, a2m1, b0n0, b0n1)
    PROD1(a0m0, a0m1, b1n0, b1n1)
    PROD1(a1m0, a1m1, b0n0, b0n1)
    PROD1(a0m0, a0m1, b0n0, b0n1)
  };
  LOADS(0, aE0, aE1, bE0, bE1)
  LOADS(1, aO0, aO1, bO0, bO1)
  CONVW2(0, aE0, aE1, bE0, bE1)
  __syncthreads();
#pragma unroll 1
  for (int kk = 0; kk < 128; kk += 2) {
    if (kk + 2 < 128) { LOADS(kk + 2, aE0, aE1, bE0, bE1) }
    __builtin_amdgcn_sched_barrier(0);
    compute(0);
    CONVW2(24576, aO0, aO1, bO0, bO1)
    __syncthreads();
    if (kk + 3 < 128) { LOADS(kk + 3, aO0, aO1, bO0, bO1) }
    __builtin_amdgcn_sched_barrier(0);
    compute(24576);
    if (kk + 2 < 128) { CONVW2(0, aE0, aE1, bE0, bE1) }
    __syncthreads();
  }
  const int t0 = bm * 64;
  float* lf2 = (float*)smem;
#define EPI(MI, NI, ACC) \
  { _Pragma("unroll") \
    for (int r = 0; r < 4; ++r) { \
      int tl = wr * 32 + (MI) * 16 + lg * 4 + r; \
      int e  = wc * 32 + (NI) * 16 + l15; \
      float v = ACC[r]; \
      outl[(size_t)(t0 + tl) * NE + e] = v; \
      lf2[tl * 65 + e] = v; \
    } }
  EPI(0, 0, acc00) EPI(0, 1, acc01) EPI(1, 0, acc10) EPI(1, 1, acc11)
#undef EPI
  __syncthreads();
  if (tid < 64) {
    const int t = tid;
    float m1 = -1e30f, m2 = -1e30f;
    int i1 = 0, i2 = 0;
#pragma unroll
    for (int e = 0; e < NE; ++e) {
      float v = lf2[t * 65 + e];
      if (v > m1)      { m2 = m1; i2 = i1; m1 = v; i1 = e; }
      else if (v > m2) { m2 = v; i2 = e; }
    }
    float e2  = expf(m2 - m1);
    float inv = 1.0f / (1.0f + e2);
    outw[(size_t)(t0 + t) * 2 + 0] = inv;
    outw[(size_t)(t0 + t) * 2 + 1] = e2 * inv;
    outi[(size_t)(t0 + t) * 2 + 0] = (float)i1;
    outi[(size_t)(t0 + t) * 2 + 1] = (float)i2;
  }
}

extern "C" void kernel_launch(void* const* d_in, const int* in_sizes, int n_in,
                              void* d_out, int out_size, void* d_ws, size_t ws_size,
                              hipStream_t stream) {
  (void)in_sizes; (void)n_in; (void)out_size;
  const float* A = (const float*)d_in[0];   // hidden_states [32768][4096] f32
  const float* W = (const float*)d_in[1];   // gate_w [64][4096] f32
  float* outw = (float*)d_out;              // [T][2] weights
  float* outi = (float*)d_out + 2 * TT;     // [T][2] indices AS FLOATS
  float* outl = (float*)d_out + 4 * TT;     // [T][64] logits

  const size_t need = (size_t)128 * 3 * 4 * 1024;   // 1.5 MiB packed B
  if (ws_size >= need) {
    hipLaunchKernelGGL(prepack_w_kernel, dim3(128), dim3(256), 0, stream,
                       W, (uint4*)d_ws);
    hipLaunchKernelGGL(router_pipe_kernel, dim3(TT / 64), dim3(NT), 0, stream,
                       A, (const uint4*)d_ws, outw, outi, outl);
  } else {
    hipLaunchKernelGGL(topk_router_lds, dim3(TT / 64), dim3(256), 0, stream,
                       A, W, outw, outi, outl);
  }
}